// Round 1
// baseline (3018.164 us; speedup 1.0000x reference)
//
#include <hip/hip_runtime.h>

constexpr int NN = 100000;   // nodes
constexpr int DI = 256;      // in features
constexpr int DO = 128;      // out features
constexpr int NE = 1600000;  // edges

// ---------------- GEMM: h = (x * mask) @ W ----------------
// block = 256 threads, tile = 64 rows x 128 cols (full N), K chunked by 64.
// LDS: xT[64][65] (transposed, pad 65 -> conflict-free) + ws[64][128] = ~49 KB.
// Each thread: 8 consecutive rows x 4 consecutive cols = 32 accumulators.
__global__ __launch_bounds__(256, 2)
void gemm_kernel(const float* __restrict__ x, const float* __restrict__ mask,
                 const float* __restrict__ W, float* __restrict__ h) {
    constexpr int KC = 64;
    __shared__ float xT[KC][65];   // [k][row]
    __shared__ float ws[KC][DO];   // [k][col]
    const int tid = threadIdx.x;
    const int m0  = blockIdx.x * 64;
    const int nc  = tid & 31;   // col group: cols nc*4 .. nc*4+3
    const int mg  = tid >> 5;   // row group: rows mg*8 .. mg*8+7

    float acc[8][4];
#pragma unroll
    for (int i = 0; i < 8; ++i)
        acc[i][0] = acc[i][1] = acc[i][2] = acc[i][3] = 0.f;

    const int lr = tid >> 4;         // 0..15 loader row
    const int lk = (tid & 15) << 2;  // loader k-offset (float4)

    for (int kc = 0; kc < DI; kc += KC) {
        // stage x*mask tile (64 rows x 64 k), transposed into LDS
#pragma unroll
        for (int rr = 0; rr < 64; rr += 16) {
            const int r = m0 + lr + rr;
            float4 xv = make_float4(0.f, 0.f, 0.f, 0.f);
            float4 mv = make_float4(0.f, 0.f, 0.f, 0.f);
            if (r < NN) {
                xv = *(const float4*)(x    + (size_t)r * DI + kc + lk);
                mv = *(const float4*)(mask + (size_t)r * DI + kc + lk);
            }
            xT[lk + 0][lr + rr] = xv.x * mv.x;
            xT[lk + 1][lr + rr] = xv.y * mv.y;
            xT[lk + 2][lr + rr] = xv.z * mv.z;
            xT[lk + 3][lr + rr] = xv.w * mv.w;
        }
        // stage W tile (64 k x 128 cols)
#pragma unroll
        for (int j = 0; j < 8; ++j) {
            const int kr = mg + 8 * j;
            *(float4*)&ws[kr][nc * 4] =
                *(const float4*)(W + (size_t)(kc + kr) * DO + nc * 4);
        }
        __syncthreads();
#pragma unroll
        for (int kk = 0; kk < KC; ++kk) {
            const float4 b = *(const float4*)&ws[kk][nc * 4];
#pragma unroll
            for (int i = 0; i < 8; ++i) {
                const float a = xT[kk][mg * 8 + i];  // half-wave broadcast
                acc[i][0] += a * b.x;
                acc[i][1] += a * b.y;
                acc[i][2] += a * b.z;
                acc[i][3] += a * b.w;
            }
        }
        __syncthreads();
    }
#pragma unroll
    for (int i = 0; i < 8; ++i) {
        const int r = m0 + mg * 8 + i;
        if (r < NN)
            *(float4*)(h + (size_t)r * DO + nc * 4) =
                make_float4(acc[i][0], acc[i][1], acc[i][2], acc[i][3]);
    }
}

// ---------------- Scatter: out[r] += w_e * h[c] ----------------
// 32 lanes per edge, each lane owns a float4 of the 128-wide feature row.
__global__ __launch_bounds__(256)
void scatter_kernel(const float* __restrict__ h, const int* __restrict__ erow,
                    const int* __restrict__ ecol, const float* __restrict__ ew,
                    float* __restrict__ out) {
    const int t    = blockIdx.x * 256 + threadIdx.x;
    const int e    = t >> 5;
    const int lane = t & 31;
    if (e >= NE) return;
    const int   r = erow[e];
    const int   c = ecol[e];
    const float w = ew[e];
    const float4 v = *(const float4*)(h + (size_t)c * DO + lane * 4);
    float* o = out + (size_t)r * DO + lane * 4;
    atomicAdd(o + 0, w * v.x);
    atomicAdd(o + 1, w * v.y);
    atomicAdd(o + 2, w * v.z);
    atomicAdd(o + 3, w * v.w);
}

// ---------------- ReLU ----------------
__global__ __launch_bounds__(256)
void relu_kernel(float* __restrict__ out, int n4) {
    const int i = blockIdx.x * 256 + threadIdx.x;
    if (i < n4) {
        float4 v = ((float4*)out)[i];
        v.x = fmaxf(v.x, 0.f);
        v.y = fmaxf(v.y, 0.f);
        v.z = fmaxf(v.z, 0.f);
        v.w = fmaxf(v.w, 0.f);
        ((float4*)out)[i] = v;
    }
}

extern "C" void kernel_launch(void* const* d_in, const int* in_sizes, int n_in,
                              void* d_out, int out_size, void* d_ws, size_t ws_size,
                              hipStream_t stream) {
    const float* x    = (const float*)d_in[0];
    const float* mask = (const float*)d_in[1];
    const float* W    = (const float*)d_in[2];
    const int*   erow = (const int*)d_in[3];
    const int*   ecol = (const int*)d_in[4];
    const float* ew   = (const float*)d_in[5];
    float* out = (float*)d_out;
    float* h   = (float*)d_ws;  // NN*DO*4 = 51.2 MB scratch

    // out must start at zero for the atomic aggregation (harness poisons it)
    hipMemsetAsync(out, 0, (size_t)NN * DO * sizeof(float), stream);

    gemm_kernel<<<(NN + 63) / 64, 256, 0, stream>>>(x, mask, W, h);
    scatter_kernel<<<(NE * 32 + 255) / 256, 256, 0, stream>>>(h, erow, ecol, ew, out);

    const int n4 = NN * DO / 4;
    relu_kernel<<<(n4 + 255) / 256, 256, 0, stream>>>(out, n4);
}

// Round 2
// 712.944 us; speedup vs baseline: 4.2334x; 4.2334x over previous
//
#include <hip/hip_runtime.h>

constexpr int NN = 100000;   // nodes
constexpr int DI = 256;      // in features
constexpr int DO = 128;      // out features
constexpr int NE = 1600000;  // edges

// ---------------- GEMM: h = (x * mask) @ W ----------------
__global__ __launch_bounds__(256, 2)
void gemm_kernel(const float* __restrict__ x, const float* __restrict__ mask,
                 const float* __restrict__ W, float* __restrict__ h) {
    constexpr int KC = 64;
    __shared__ float xT[KC][65];   // [k][row], pad -> conflict-free
    __shared__ float ws[KC][DO];   // [k][col]
    const int tid = threadIdx.x;
    const int m0  = blockIdx.x * 64;
    const int nc  = tid & 31;   // cols nc*4 .. nc*4+3
    const int mg  = tid >> 5;   // rows mg*8 .. mg*8+7

    float acc[8][4];
#pragma unroll
    for (int i = 0; i < 8; ++i)
        acc[i][0] = acc[i][1] = acc[i][2] = acc[i][3] = 0.f;

    const int lr = tid >> 4;         // loader row 0..15
    const int lk = (tid & 15) << 2;  // loader k-offset (float4)

    for (int kc = 0; kc < DI; kc += KC) {
#pragma unroll
        for (int rr = 0; rr < 64; rr += 16) {
            const int r = m0 + lr + rr;
            float4 xv = make_float4(0.f, 0.f, 0.f, 0.f);
            float4 mv = make_float4(0.f, 0.f, 0.f, 0.f);
            if (r < NN) {
                xv = *(const float4*)(x    + (size_t)r * DI + kc + lk);
                mv = *(const float4*)(mask + (size_t)r * DI + kc + lk);
            }
            xT[lk + 0][lr + rr] = xv.x * mv.x;
            xT[lk + 1][lr + rr] = xv.y * mv.y;
            xT[lk + 2][lr + rr] = xv.z * mv.z;
            xT[lk + 3][lr + rr] = xv.w * mv.w;
        }
#pragma unroll
        for (int j = 0; j < 8; ++j) {
            const int kr = mg + 8 * j;
            *(float4*)&ws[kr][nc * 4] =
                *(const float4*)(W + (size_t)(kc + kr) * DO + nc * 4);
        }
        __syncthreads();
#pragma unroll
        for (int kk = 0; kk < KC; ++kk) {
            const float4 b = *(const float4*)&ws[kk][nc * 4];
#pragma unroll
            for (int i = 0; i < 8; ++i) {
                const float a = xT[kk][mg * 8 + i];
                acc[i][0] += a * b.x;
                acc[i][1] += a * b.y;
                acc[i][2] += a * b.z;
                acc[i][3] += a * b.w;
            }
        }
        __syncthreads();
    }
#pragma unroll
    for (int i = 0; i < 8; ++i) {
        const int r = m0 + mg * 8 + i;
        if (r < NN)
            *(float4*)(h + (size_t)r * DO + nc * 4) =
                make_float4(acc[i][0], acc[i][1], acc[i][2], acc[i][3]);
    }
}

// ---------------- CSR build: histogram ----------------
__global__ __launch_bounds__(256)
void hist_kernel(const int* __restrict__ erow, int* __restrict__ cnt) {
    const int e = blockIdx.x * 256 + threadIdx.x;
    if (e < NE) atomicAdd(&cnt[erow[e]], 1);
}

// ---------------- CSR build: exclusive scan (single block, 1024 thr) ------
__global__ __launch_bounds__(1024)
void scan_kernel(const int* __restrict__ cnt, int* __restrict__ row_start,
                 int* __restrict__ cursor) {
    __shared__ int wsum[16];
    const int t    = threadIdx.x;
    const int lane = t & 63;
    const int wid  = t >> 6;
    int running = 0;
    for (int base = 0; base <= NN; base += 1024) {
        const int idx = base + t;
        const int c = (idx < NN) ? cnt[idx] : 0;
        int v = c;
#pragma unroll
        for (int off = 1; off < 64; off <<= 1) {
            const int n = __shfl_up(v, off, 64);
            if (lane >= off) v += n;
        }
        if (lane == 63) wsum[wid] = v;
        __syncthreads();
        int p = 0, tot = 0;
#pragma unroll
        for (int i = 0; i < 16; ++i) {
            const int s = wsum[i];
            tot += s;
            if (i < wid) p += s;
        }
        const int excl = running + p + (v - c);
        if (idx <= NN) row_start[idx] = excl;
        if (idx < NN)  cursor[idx]    = excl;
        running += tot;
        __syncthreads();  // wsum reused next chunk
    }
}

// ---------------- CSR build: fill ----------------
__global__ __launch_bounds__(256)
void fill_kernel(const int* __restrict__ erow, const int* __restrict__ ecol,
                 const float* __restrict__ ew, int* __restrict__ cursor,
                 int* __restrict__ csr_col, float* __restrict__ csr_w) {
    const int e = blockIdx.x * 256 + threadIdx.x;
    if (e >= NE) return;
    const int p = atomicAdd(&cursor[erow[e]], 1);
    csr_col[p] = ecol[e];
    csr_w[p]   = ew[e];
}

// ---------------- Gather + ReLU: out[r] = relu(sum_e w*h[col]) ----------------
// 32 lanes per row; lane owns one float4 of the 128-wide feature row.
__global__ __launch_bounds__(256)
void gather_kernel(const float* __restrict__ h, const int* __restrict__ row_start,
                   const int* __restrict__ csr_col, const float* __restrict__ csr_w,
                   float* __restrict__ out) {
    const int t    = blockIdx.x * 256 + threadIdx.x;
    const int row  = t >> 5;
    const int lane = t & 31;
    if (row >= NN) return;
    const int start = row_start[row];
    const int end   = row_start[row + 1];
    const float4* h4 = (const float4*)h;

    float4 acc = make_float4(0.f, 0.f, 0.f, 0.f);
    int j = start;
    for (; j + 4 <= end; j += 4) {
        const int c0 = csr_col[j], c1 = csr_col[j + 1],
                  c2 = csr_col[j + 2], c3 = csr_col[j + 3];
        const float w0 = csr_w[j], w1 = csr_w[j + 1],
                    w2 = csr_w[j + 2], w3 = csr_w[j + 3];
        const float4 v0 = h4[(size_t)c0 * 32 + lane];
        const float4 v1 = h4[(size_t)c1 * 32 + lane];
        const float4 v2 = h4[(size_t)c2 * 32 + lane];
        const float4 v3 = h4[(size_t)c3 * 32 + lane];
        acc.x += w0 * v0.x + w1 * v1.x + w2 * v2.x + w3 * v3.x;
        acc.y += w0 * v0.y + w1 * v1.y + w2 * v2.y + w3 * v3.y;
        acc.z += w0 * v0.z + w1 * v1.z + w2 * v2.z + w3 * v3.z;
        acc.w += w0 * v0.w + w1 * v1.w + w2 * v2.w + w3 * v3.w;
    }
    for (; j < end; ++j) {
        const int   c = csr_col[j];
        const float w = csr_w[j];
        const float4 v = h4[(size_t)c * 32 + lane];
        acc.x += w * v.x; acc.y += w * v.y;
        acc.z += w * v.z; acc.w += w * v.w;
    }
    acc.x = fmaxf(acc.x, 0.f);
    acc.y = fmaxf(acc.y, 0.f);
    acc.z = fmaxf(acc.z, 0.f);
    acc.w = fmaxf(acc.w, 0.f);
    ((float4*)out)[(size_t)row * 32 + lane] = acc;
}

extern "C" void kernel_launch(void* const* d_in, const int* in_sizes, int n_in,
                              void* d_out, int out_size, void* d_ws, size_t ws_size,
                              hipStream_t stream) {
    const float* x    = (const float*)d_in[0];
    const float* mask = (const float*)d_in[1];
    const float* W    = (const float*)d_in[2];
    const int*   erow = (const int*)d_in[3];
    const int*   ecol = (const int*)d_in[4];
    const float* ew   = (const float*)d_in[5];
    float* out = (float*)d_out;

    // workspace layout (16B-aligned chunks)
    char* ws_p = (char*)d_ws;
    float* h         = (float*)ws_p;                 ws_p += (size_t)NN * DO * 4;   // 51.2 MB
    int*   cnt       = (int*)ws_p;                   ws_p += (size_t)NN * 4;        // 400 KB
    int*   row_start = (int*)ws_p;                   ws_p += (size_t)(NN + 4) * 4;  // 400 KB
    int*   cursor    = (int*)ws_p;                   ws_p += (size_t)NN * 4;        // 400 KB
    int*   csr_col   = (int*)ws_p;                   ws_p += (size_t)NE * 4;        // 6.4 MB
    float* csr_w     = (float*)ws_p;                                                // 6.4 MB

    hipMemsetAsync(cnt, 0, (size_t)NN * sizeof(int), stream);

    gemm_kernel<<<(NN + 63) / 64, 256, 0, stream>>>(x, mask, W, h);
    hist_kernel<<<(NE + 255) / 256, 256, 0, stream>>>(erow, cnt);
    scan_kernel<<<1, 1024, 0, stream>>>(cnt, row_start, cursor);
    fill_kernel<<<(NE + 255) / 256, 256, 0, stream>>>(erow, ecol, ew, cursor,
                                                      csr_col, csr_w);
    gather_kernel<<<(NN * 32 + 255) / 256, 256, 0, stream>>>(h, row_start,
                                                             csr_col, csr_w, out);
}

// Round 3
// 525.765 us; speedup vs baseline: 5.7405x; 1.3560x over previous
//
#include <hip/hip_runtime.h>

constexpr int NN = 100000;   // nodes
constexpr int DI = 256;      // in features
constexpr int DO = 128;      // out features
constexpr int NE = 1600000;  // edges

typedef __bf16 bf16x8 __attribute__((ext_vector_type(8)));
typedef float  f32x4  __attribute__((ext_vector_type(4)));

__device__ inline unsigned short f2bf(float f) {
    union { float f; unsigned u; } v; v.f = f;
    return (unsigned short)((v.u + 0x7FFF + ((v.u >> 16) & 1)) >> 16);
}
__device__ inline float bf2f(unsigned short u) {
    union { unsigned u; float f; } v; v.u = ((unsigned)u) << 16;
    return v.f;
}

// ---------------- W transpose: W[256][128] f32 -> Wt[128][256] bf16 ----------
__global__ __launch_bounds__(256)
void wt_kernel(const float* __restrict__ W, unsigned short* __restrict__ Wt) {
    __shared__ float t[32][33];
    const int tx = threadIdx.x & 31, ty = threadIdx.x >> 5;  // ty 0..7
    const int k0 = (blockIdx.x >> 2) * 32, n0 = (blockIdx.x & 3) * 32;
#pragma unroll
    for (int i = 0; i < 32; i += 8)
        t[ty + i][tx] = W[(size_t)(k0 + ty + i) * DO + n0 + tx];
    __syncthreads();
#pragma unroll
    for (int i = 0; i < 32; i += 8)
        Wt[(size_t)(n0 + ty + i) * DI + k0 + tx] = f2bf(t[tx][ty + i]);
}

// ---------------- GEMM: h = bf16( (x*mask) @ W ), MFMA ----------------
// block 256 (4 waves), tile 128 rows x 128 cols, BK=64.
// LDS stride 72 bf16 = 144 B: 16B-aligned b128, ~2-way conflicts max.
__global__ __launch_bounds__(256)
void gemm_kernel(const float* __restrict__ x, const float* __restrict__ mask,
                 const unsigned short* __restrict__ Wt,
                 unsigned short* __restrict__ h) {
    __shared__ unsigned short As[128][72];
    __shared__ unsigned short Bs[128][72];
    const int tid  = threadIdx.x;
    const int lane = tid & 63;
    const int w    = tid >> 6;          // wave 0..3
    const int m0   = blockIdx.x * 128;
    const int mw   = w * 32;            // wave's row base in tile
    const int l15  = lane & 15;
    const int l4   = lane >> 4;

    f32x4 acc[2][8];
#pragma unroll
    for (int rt = 0; rt < 2; ++rt)
#pragma unroll
        for (int ct = 0; ct < 8; ++ct) acc[rt][ct] = (f32x4){0.f, 0.f, 0.f, 0.f};

    for (int kc = 0; kc < DI; kc += 64) {
        // stage A: x*mask tile 128 rows x 64 k -> bf16
        {
            const int kl = (tid & 15) * 4;
#pragma unroll
            for (int p = 0; p < 8; ++p) {
                const int r = p * 16 + (tid >> 4);
                float4 xv = make_float4(0.f, 0.f, 0.f, 0.f);
                float4 mv = make_float4(0.f, 0.f, 0.f, 0.f);
                if (m0 + r < NN) {
                    xv = *(const float4*)(x    + (size_t)(m0 + r) * DI + kc + kl);
                    mv = *(const float4*)(mask + (size_t)(m0 + r) * DI + kc + kl);
                }
                ushort4 pk;
                pk.x = f2bf(xv.x * mv.x); pk.y = f2bf(xv.y * mv.y);
                pk.z = f2bf(xv.z * mv.z); pk.w = f2bf(xv.w * mv.w);
                *(ushort4*)&As[r][kl] = pk;
            }
        }
        // stage B: Wt tile 128 n x 64 k (already bf16, coalesced 16B)
        {
            const int kl = (tid & 7) * 8;
#pragma unroll
            for (int p = 0; p < 4; ++p) {
                const int n = p * 32 + (tid >> 3);
                *(uint4*)&Bs[n][kl] =
                    *(const uint4*)(Wt + (size_t)n * DI + kc + kl);
            }
        }
        __syncthreads();
#pragma unroll
        for (int ks = 0; ks < 2; ++ks) {
            const int ko = ks * 32 + l4 * 8;
            bf16x8 a0 = *(const bf16x8*)&As[mw + l15][ko];
            bf16x8 a1 = *(const bf16x8*)&As[mw + 16 + l15][ko];
#pragma unroll
            for (int ct = 0; ct < 8; ++ct) {
                bf16x8 b = *(const bf16x8*)&Bs[ct * 16 + l15][ko];
                acc[0][ct] = __builtin_amdgcn_mfma_f32_16x16x32_bf16(a0, b, acc[0][ct], 0, 0, 0);
                acc[1][ct] = __builtin_amdgcn_mfma_f32_16x16x32_bf16(a1, b, acc[1][ct], 0, 0, 0);
            }
        }
        __syncthreads();
    }
    // epilogue: D[row=(lane>>4)*4+reg][col=lane&15]
#pragma unroll
    for (int rt = 0; rt < 2; ++rt)
#pragma unroll
        for (int ct = 0; ct < 8; ++ct)
#pragma unroll
            for (int reg = 0; reg < 4; ++reg) {
                const int row = m0 + mw + rt * 16 + l4 * 4 + reg;
                if (row < NN)
                    h[(size_t)row * DO + ct * 16 + l15] = f2bf(acc[rt][ct][reg]);
            }
}

// ---------------- CSR build ----------------
__global__ __launch_bounds__(256)
void hist_kernel(const int* __restrict__ erow, int* __restrict__ cnt) {
    const int e = blockIdx.x * 256 + threadIdx.x;
    if (e < NE) atomicAdd(&cnt[erow[e]], 1);
}

__global__ __launch_bounds__(1024)
void scan1_kernel(const int* __restrict__ cnt, int* __restrict__ lscan,
                  int* __restrict__ bsum) {
    __shared__ int wsum[16];
    const int t = threadIdx.x;
    const int idx = blockIdx.x * 1024 + t;
    const int lane = t & 63, wid = t >> 6;
    const int c = (idx < NN) ? cnt[idx] : 0;
    int v = c;
#pragma unroll
    for (int off = 1; off < 64; off <<= 1) {
        const int n = __shfl_up(v, off, 64);
        if (lane >= off) v += n;
    }
    if (lane == 63) wsum[wid] = v;
    __syncthreads();
    int p = 0, tot = 0;
#pragma unroll
    for (int i = 0; i < 16; ++i) {
        const int s = wsum[i];
        tot += s;
        if (i < wid) p += s;
    }
    if (idx < NN) lscan[idx] = p + v - c;
    if (t == 0) bsum[blockIdx.x] = tot;
}

__global__ __launch_bounds__(128)
void scan2_kernel(const int* __restrict__ bsum, int* __restrict__ bbase, int nb) {
    __shared__ int w0tot;
    const int t = threadIdx.x;
    const int lane = t & 63, wid = t >> 6;
    const int v0 = (t < nb) ? bsum[t] : 0;
    int v = v0;
#pragma unroll
    for (int off = 1; off < 64; off <<= 1) {
        const int n = __shfl_up(v, off, 64);
        if (lane >= off) v += n;
    }
    if (wid == 0 && lane == 63) w0tot = v;
    __syncthreads();
    const int excl = v - v0 + (wid ? w0tot : 0);
    if (t < nb) bbase[t] = excl;
}

__global__ __launch_bounds__(1024)
void scan3_kernel(const int* __restrict__ lscan, const int* __restrict__ bbase,
                  int* __restrict__ row_start, int* __restrict__ cursor) {
    const int idx = blockIdx.x * 1024 + threadIdx.x;
    if (idx < NN) {
        const int v = lscan[idx] + bbase[blockIdx.x];
        row_start[idx] = v;
        cursor[idx]    = v;
    } else if (idx == NN) {
        row_start[NN] = NE;
    }
}

__global__ __launch_bounds__(256)
void fill_kernel(const int* __restrict__ erow, const int* __restrict__ ecol,
                 const float* __restrict__ ew, int* __restrict__ cursor,
                 int2* __restrict__ csr) {
    const int e = blockIdx.x * 256 + threadIdx.x;
    if (e >= NE) return;
    const int p = atomicAdd(&cursor[erow[e]], 1);
    int2 v;
    v.x = ecol[e];
    v.y = __float_as_int(ew[e]);
    csr[p] = v;
}

// ---------------- Gather + ReLU ----------------
// 16 lanes per row; lane owns 8 of the 128 features (16B bf16 loads).
__global__ __launch_bounds__(256)
void gather_kernel(const unsigned short* __restrict__ h,
                   const int* __restrict__ row_start,
                   const int2* __restrict__ csr, float* __restrict__ out) {
    const int t    = blockIdx.x * 256 + threadIdx.x;
    const int row  = t >> 4;
    const int lane = t & 15;
    if (row >= NN) return;
    const int start = row_start[row];
    const int end   = row_start[row + 1];

    float acc[8];
#pragma unroll
    for (int i = 0; i < 8; ++i) acc[i] = 0.f;

    int j = start;
    for (; j + 2 <= end; j += 2) {
        const int2 cw0 = csr[j], cw1 = csr[j + 1];
        const float w0 = __int_as_float(cw0.y);
        const float w1 = __int_as_float(cw1.y);
        const uint4 q0 = *(const uint4*)(h + (size_t)cw0.x * DO + lane * 8);
        const uint4 q1 = *(const uint4*)(h + (size_t)cw1.x * DO + lane * 8);
        const unsigned* u0 = (const unsigned*)&q0;
        const unsigned* u1 = (const unsigned*)&q1;
#pragma unroll
        for (int i = 0; i < 4; ++i) {
            acc[2 * i + 0] += w0 * bf2f((unsigned short)(u0[i] & 0xFFFF))
                            + w1 * bf2f((unsigned short)(u1[i] & 0xFFFF));
            acc[2 * i + 1] += w0 * bf2f((unsigned short)(u0[i] >> 16))
                            + w1 * bf2f((unsigned short)(u1[i] >> 16));
        }
    }
    if (j < end) {
        const int2 cw = csr[j];
        const float w = __int_as_float(cw.y);
        const uint4 q = *(const uint4*)(h + (size_t)cw.x * DO + lane * 8);
        const unsigned* u = (const unsigned*)&q;
#pragma unroll
        for (int i = 0; i < 4; ++i) {
            acc[2 * i + 0] += w * bf2f((unsigned short)(u[i] & 0xFFFF));
            acc[2 * i + 1] += w * bf2f((unsigned short)(u[i] >> 16));
        }
    }
    float4 o0 = make_float4(fmaxf(acc[0], 0.f), fmaxf(acc[1], 0.f),
                            fmaxf(acc[2], 0.f), fmaxf(acc[3], 0.f));
    float4 o1 = make_float4(fmaxf(acc[4], 0.f), fmaxf(acc[5], 0.f),
                            fmaxf(acc[6], 0.f), fmaxf(acc[7], 0.f));
    float* op = out + (size_t)row * DO + lane * 8;
    *(float4*)(op + 0) = o0;
    *(float4*)(op + 4) = o1;
}

extern "C" void kernel_launch(void* const* d_in, const int* in_sizes, int n_in,
                              void* d_out, int out_size, void* d_ws, size_t ws_size,
                              hipStream_t stream) {
    const float* x    = (const float*)d_in[0];
    const float* mask = (const float*)d_in[1];
    const float* W    = (const float*)d_in[2];
    const int*   erow = (const int*)d_in[3];
    const int*   ecol = (const int*)d_in[4];
    const float* ew   = (const float*)d_in[5];
    float* out = (float*)d_out;

    char* p = (char*)d_ws;
    unsigned short* h  = (unsigned short*)p;  p += (size_t)NN * DO * 2;   // 25.6 MB
    unsigned short* Wt = (unsigned short*)p;  p += (size_t)DO * DI * 2;   // 64 KB
    int* cnt       = (int*)p;                 p += (size_t)NN * 4;        // 400 KB
    int* row_start = (int*)p;                 p += (size_t)(NN + 4) * 4;
    int* cursor    = (int*)p;                 p += (size_t)NN * 4;
    int* lscan     = (int*)p;                 p += (size_t)NN * 4;
    int* bsum      = (int*)p;                 p += 512;
    int* bbase     = (int*)p;                 p += 512;
    int2* csr      = (int2*)p;                                           // 12.8 MB

    constexpr int NB = (NN + 1023) / 1024;  // 98 scan blocks

    hipMemsetAsync(cnt, 0, (size_t)NN * sizeof(int), stream);

    wt_kernel<<<32, 256, 0, stream>>>(W, Wt);
    gemm_kernel<<<(NN + 127) / 128, 256, 0, stream>>>(x, mask, Wt, h);
    hist_kernel<<<(NE + 255) / 256, 256, 0, stream>>>(erow, cnt);
    scan1_kernel<<<NB, 1024, 0, stream>>>(cnt, lscan, bsum);
    scan2_kernel<<<1, 128, 0, stream>>>(bsum, bbase, NB);
    scan3_kernel<<<NB, 1024, 0, stream>>>(lscan, bbase, row_start, cursor);
    fill_kernel<<<(NE + 255) / 256, 256, 0, stream>>>(erow, ecol, ew, cursor, csr);
    gather_kernel<<<(NN * 16 + 255) / 256, 256, 0, stream>>>(h, row_start, csr, out);
}